// Round 2
// baseline (581.035 us; speedup 1.0000x reference)
//
#include <hip/hip_runtime.h>
#include <hip/hip_bf16.h>
#include <cstdint>
#include <cstddef>

#define B_    4
#define K_    2048
#define N_    8192
#define NBR_  32
#define NCAND 40      // candidate superset size (top-40 by truncated key)
#define CIN   16
#define WHID  32
#define CMID  16
#define FHID  64
#define COUT  64

// ---------------------------------------------------------------------------
// Detect element width of `valid` (bool/u8 vs int32/f32). Words of a u8
// bernoulli(0.95) array look "byte-packed" (set bits in upper 3 bytes);
// int32 {0,1} and f32 {0,1.0f} words never do. Runs every launch
// (graph-safe; deterministic data -> deterministic flag).
// ---------------------------------------------------------------------------
__global__ void pc_detect_kernel(const unsigned* __restrict__ v, int* __restrict__ flag) {
    if (threadIdx.x == 0 && blockIdx.x == 0) {
        int byte_like = 0;
        for (int i = 0; i < 64; ++i) {
            unsigned w = v[i];
            if (((w & 0xFEFEFEFEu) == 0u) && ((w & 0xFFFFFF00u) != 0u)) byte_like = 1;
        }
        *flag = byte_like;
    }
}

__device__ __forceinline__ unsigned umin_(unsigned a, unsigned b) { return a < b ? a : b; }
__device__ __forceinline__ unsigned umax_(unsigned a, unsigned b) { return a < b ? b : a; }

__device__ __forceinline__ void insert8(unsigned (&sa)[8], unsigned kv) {
    if (kv < sa[7]) {
#pragma unroll
        for (int i = 0; i < 8; ++i) {
            unsigned lo = umin_(sa[i], kv);
            kv = umax_(sa[i], kv);
            sa[i] = lo;
        }
    }
}

// Truncated sortable key: top 19 bits of d^2 (positive f32 -> monotone as
// uint) | 13-bit idx. Used only to build a candidate SUPERSET; exact ranking
// happens in the refine step with full-precision d^2.
template <typename VT>
__device__ __forceinline__ void scan_pts(const float* __restrict__ pts,
                                         const VT* __restrict__ vp,
                                         float kx, float ky, float kz,
                                         int lane, unsigned (&sa)[8]) {
#pragma unroll 2
    for (int t = 0; t < N_ / 64; ++t) {
        const int n = t * 64 + lane;
        const float px = pts[n * 3 + 0];
        const float py = pts[n * 3 + 1];
        const float pz = pts[n * 3 + 2];
        const float dx = px - kx, dy = py - ky, dz = pz - kz;
        const float d2 = fmaf(dz, dz, fmaf(dy, dy, dx * dx));
        const bool v = (vp[n] != (VT)0);
        const unsigned kv = v ? ((__float_as_uint(d2) & 0xFFFFE000u) | (unsigned)n)
                              : 0xFFFFFFFFu;
        insert8(sa, kv);
    }
}

__global__ __launch_bounds__(64) void pc_main_kernel(
    const float* __restrict__ keys,   // [B,K,3]
    const float* __restrict__ points, // [B,N,3]
    const float* __restrict__ feats,  // [B,N,CIN]
    const void*  __restrict__ validp, // [B,K,N] u8 or u32
    const float* __restrict__ ww1, const float* __restrict__ wb1,
    const float* __restrict__ ww2, const float* __restrict__ wb2,
    const float* __restrict__ fw1, const float* __restrict__ fb1,
    const float* __restrict__ fw2, const float* __restrict__ fb2,
    float* __restrict__ out,          // [B,K,COUT]
    const int* __restrict__ flagp)
{
    __shared__ float    s_ww2[WHID * CMID]; // 512 f
    __shared__ unsigned s_cand[8 * 64];     // 2 KB
    __shared__ unsigned s_slot[NBR_];       // final selected neighbors
    __shared__ float    s_w[NBR_ * CMID];   // 512 f
    __shared__ float    s_nf[NBR_ * CIN];   // 512 f
    __shared__ float    s_e[CMID * CIN];    // 256 f
    __shared__ float    s_hp[4 * FHID];     // 256 f
    __shared__ float    s_hf[FHID];         // 64 f

    const int lane = threadIdx.x;
    const int row  = blockIdx.x;       // b*K + k
    const int b    = row >> 11;        // K = 2048

    // stage ww2 into LDS (one-time)
#pragma unroll
    for (int i = 0; i < (WHID * CMID) / 64; ++i)
        s_ww2[i * 64 + lane] = ww2[i * 64 + lane];

    const float kx = keys[row * 3 + 0];
    const float ky = keys[row * 3 + 1];
    const float kz = keys[row * 3 + 2];
    const float* pts = points + (size_t)b * N_ * 3;
    const int flag = *flagp;

    // ---------------- phase 1: per-lane top-8 over 128 points ----------------
    unsigned sa[8];
#pragma unroll
    for (int i = 0; i < 8; ++i) sa[i] = 0xFFFFFFFFu;

    const size_t vbase = (size_t)row * N_;
    if (flag) {
        scan_pts<unsigned char>(pts, (const unsigned char*)validp + vbase, kx, ky, kz, lane, sa);
    } else {
        scan_pts<unsigned>(pts, (const unsigned*)validp + vbase, kx, ky, kz, lane, sa);
    }

    // -------- merge: NCAND-round wave-wide extract-min (candidate superset) --------
#pragma unroll
    for (int i = 0; i < 8; ++i) s_cand[i * 64 + lane] = sa[i];
    __syncthreads();

    unsigned cur   = sa[0];
    int      head  = 0;
    unsigned mykey = 0xFFFFFFFFu;
#pragma unroll 4
    for (int r = 0; r < NCAND; ++r) {
        unsigned t = cur;
#pragma unroll
        for (int off = 1; off < 64; off <<= 1)
            t = umin_(t, (unsigned)__shfl_xor((int)t, off, 64));
        if (lane == r) mykey = t;   // lane r owns the r-th smallest (truncated order)
        if (cur == t) {             // unique winner (idx embedded in key)
            ++head;
            cur = (head < 8) ? s_cand[head * 64 + lane] : 0xFFFFFFFFu;
        }
    }

    // -------- refine: exact rank of the NCAND candidates by full-precision d^2 --------
    if (lane < NBR_) s_slot[lane] = 0xFFFFFFFFu;
    __syncthreads();

    {
        const bool fin  = (mykey < 0xF0000000u);
        const int  cidx = (int)(mykey & 8191u);
        float cd2 = 3.0e38f;
        if (fin) {
            const float cdx = pts[cidx * 3 + 0] - kx;
            const float cdy = pts[cidx * 3 + 1] - ky;
            const float cdz = pts[cidx * 3 + 2] - kz;
            cd2 = fmaf(cdz, cdz, fmaf(cdy, cdy, cdx * cdx));
        }
        const unsigned long long fkey =
            fin ? (((unsigned long long)__float_as_uint(cd2) << 13) | (unsigned long long)cidx)
                : ~0ull;
        int rank = 0;
#pragma unroll 8
        for (int j = 0; j < NCAND; ++j) {
            const unsigned long long fj = (unsigned long long)__shfl((long long)fkey, j, 64);
            rank += (fj < fkey) ? 1 : 0;
        }
        if (lane < NCAND && fin && rank < NBR_)
            s_slot[rank] = mykey;   // idx embedded; ranks of finite cands are unique
    }
    __syncthreads();

    // ---------------- phase 2a: per-neighbor weight MLP ----------------
    // lane -> (neighbor q = lane&31, half = lane>>5 owning 8 of 16 outputs)
    const int q    = lane & 31;
    const int half = lane >> 5;
    const unsigned skey = s_slot[q];
    const int   nidx = (int)(skey & 8191u);
    const float vf   = (skey < 0xF0000000u) ? 1.0f : 0.0f;

    const float rx = pts[nidx * 3 + 0] - kx;
    const float ry = pts[nidx * 3 + 1] - ky;
    const float rz = pts[nidx * 3 + 2] - kz;

    float wacc[8];
#pragma unroll
    for (int m = 0; m < 8; ++m)
        wacc[m] = half ? wb2[8 + m] : wb2[m];

#pragma unroll
    for (int j = 0; j < WHID; ++j) {
        float hj = fmaf(rx, ww1[j], fmaf(ry, ww1[WHID + j], fmaf(rz, ww1[2 * WHID + j], wb1[j])));
        hj = fmaxf(hj, 0.0f);
        const float4 wa = *(const float4*)&s_ww2[j * CMID + half * 8 + 0];
        const float4 wb = *(const float4*)&s_ww2[j * CMID + half * 8 + 4];
        wacc[0] = fmaf(hj, wa.x, wacc[0]);
        wacc[1] = fmaf(hj, wa.y, wacc[1]);
        wacc[2] = fmaf(hj, wa.z, wacc[2]);
        wacc[3] = fmaf(hj, wa.w, wacc[3]);
        wacc[4] = fmaf(hj, wb.x, wacc[4]);
        wacc[5] = fmaf(hj, wb.y, wacc[5]);
        wacc[6] = fmaf(hj, wb.z, wacc[6]);
        wacc[7] = fmaf(hj, wb.w, wacc[7]);
    }
#pragma unroll
    for (int m = 0; m < 8; ++m) wacc[m] *= vf;

    *(float4*)&s_w[q * CMID + half * 8 + 0] = make_float4(wacc[0], wacc[1], wacc[2], wacc[3]);
    *(float4*)&s_w[q * CMID + half * 8 + 4] = make_float4(wacc[4], wacc[5], wacc[6], wacc[7]);

    // neighbor feats (8 channels per lane-half); masking w alone is sufficient
    const float* fp = feats + ((size_t)b * N_ + (size_t)nidx) * CIN + half * 8;
    *(float4*)&s_nf[q * CIN + half * 8 + 0] = *(const float4*)(fp + 0);
    *(float4*)&s_nf[q * CIN + half * 8 + 4] = *(const float4*)(fp + 4);
    __syncthreads();

    // ---------------- phase 2b: e[m][c] = sum_q w[q][m]*nf[q][c] ----------------
    {
        const int m  = lane >> 2;  // 0..15
        const int c4 = lane & 3;   // c block
        float4 eacc = make_float4(0.f, 0.f, 0.f, 0.f);
#pragma unroll
        for (int qq = 0; qq < NBR_; ++qq) {
            const float  wq = s_w[qq * CMID + m];
            const float4 f  = *(const float4*)&s_nf[qq * CIN + c4 * 4];
            eacc.x = fmaf(wq, f.x, eacc.x);
            eacc.y = fmaf(wq, f.y, eacc.y);
            eacc.z = fmaf(wq, f.z, eacc.z);
            eacc.w = fmaf(wq, f.w, eacc.w);
        }
        *(float4*)&s_e[m * CIN + c4 * 4] = eacc;
    }
    __syncthreads();

    // ---------------- phase 2c: hf = relu(e_flat @ fw1 + fb1) ----------------
    {
        const int g  = lane >> 4;  // e-chunk 64*g..64*g+63
        const int t4 = lane & 15;  // outputs 4*t4..4*t4+3
        float a0 = 0.f, a1 = 0.f, a2 = 0.f, a3 = 0.f;
#pragma unroll 8
        for (int i = 0; i < 64; ++i) {
            const float  ev = s_e[g * 64 + i];
            const float4 wv = *(const float4*)&fw1[(size_t)(g * 64 + i) * FHID + t4 * 4];
            a0 = fmaf(ev, wv.x, a0);
            a1 = fmaf(ev, wv.y, a1);
            a2 = fmaf(ev, wv.z, a2);
            a3 = fmaf(ev, wv.w, a3);
        }
        *(float4*)&s_hp[g * FHID + t4 * 4] = make_float4(a0, a1, a2, a3);
    }
    __syncthreads();

    {
        float hf = fb1[lane] + s_hp[lane] + s_hp[FHID + lane] + s_hp[2 * FHID + lane] + s_hp[3 * FHID + lane];
        s_hf[lane] = fmaxf(hf, 0.0f);
    }
    __syncthreads();

    // ---------------- phase 2d: out = hf @ fw2 + fb2 ----------------
    {
        float oacc = fb2[lane];
#pragma unroll 8
        for (int j = 0; j < FHID; ++j)
            oacc = fmaf(s_hf[j], fw2[(size_t)j * COUT + lane], oacc);
        out[(size_t)row * COUT + lane] = oacc;
    }
}

extern "C" void kernel_launch(void* const* d_in, const int* in_sizes, int n_in,
                              void* d_out, int out_size, void* d_ws, size_t ws_size,
                              hipStream_t stream) {
    const float* keys   = (const float*)d_in[0];
    const float* points = (const float*)d_in[1];
    const float* feats  = (const float*)d_in[2];
    const void*  valid  = d_in[3];
    const float* ww1 = (const float*)d_in[4];
    const float* wb1 = (const float*)d_in[5];
    const float* ww2 = (const float*)d_in[6];
    const float* wb2 = (const float*)d_in[7];
    const float* fw1 = (const float*)d_in[8];
    const float* fb1 = (const float*)d_in[9];
    const float* fw2 = (const float*)d_in[10];
    const float* fb2 = (const float*)d_in[11];
    float* out = (float*)d_out;
    int*   flag = (int*)d_ws;

    pc_detect_kernel<<<1, 64, 0, stream>>>((const unsigned*)valid, flag);
    pc_main_kernel<<<B_ * K_, 64, 0, stream>>>(keys, points, feats, valid,
                                               ww1, wb1, ww2, wb2,
                                               fw1, fb1, fw2, fb2,
                                               out, flag);
}

// Round 3
// 444.263 us; speedup vs baseline: 1.3079x; 1.3079x over previous
//
#include <hip/hip_runtime.h>
#include <hip/hip_bf16.h>
#include <cstdint>
#include <cstddef>

#define B_    4
#define K_    2048
#define N_    8192
#define NBR_  32
#define NCAND 40      // candidate superset size (top-40 by truncated key)
#define CIN   16
#define WHID  32
#define CMID  16
#define FHID  64
#define COUT  64

// ---------------------------------------------------------------------------
// Detect element width of `valid` (bool/u8 vs int32/f32). Words of a u8
// bernoulli(0.95) array look "byte-packed" (set bits in upper 3 bytes);
// int32 {0,1} and f32 {0,1.0f} words never do. Runs every launch
// (graph-safe; deterministic data -> deterministic flag).
// ---------------------------------------------------------------------------
__global__ void pc_detect_kernel(const unsigned* __restrict__ v, int* __restrict__ flag) {
    const unsigned w = v[threadIdx.x & 63];
    const int byte_like = (((w & 0xFEFEFEFEu) == 0u) && ((w & 0xFFFFFF00u) != 0u)) ? 1 : 0;
    const unsigned long long m = __ballot(byte_like);
    if (threadIdx.x == 0) *flag = (m != 0ull) ? 1 : 0;
}

__device__ __forceinline__ unsigned umin_(unsigned a, unsigned b) { return a < b ? a : b; }
__device__ __forceinline__ unsigned umax_(unsigned a, unsigned b) { return a < b ? b : a; }

__device__ __forceinline__ void insert8(unsigned (&sa)[8], unsigned kv) {
    if (kv < sa[7]) {
#pragma unroll
        for (int i = 0; i < 8; ++i) {
            unsigned lo = umin_(sa[i], kv);
            kv = umax_(sa[i], kv);
            sa[i] = lo;
        }
    }
}

// Truncated sortable key: top 19 bits of d^2 (positive f32 -> monotone as
// uint) | 13-bit idx. Candidate SUPERSET only; exact ranking in refine.
// 4 points per lane per iteration: valid as packed u32 (BYTE=1) or uint4.
template <int BYTE>
__device__ __forceinline__ void scan_pts4(const float* __restrict__ pts,
                                          const void* __restrict__ vpv,
                                          float kx, float ky, float kz,
                                          int lane, unsigned (&sa)[8]) {
#pragma unroll 2
    for (int t = 0; t < N_ / 256; ++t) {
        const int n0 = t * 256 + lane * 4;
        const float4* p4 = (const float4*)(pts + (size_t)n0 * 3);
        const float4 A = p4[0];   // x0 y0 z0 x1
        const float4 Bv = p4[1];  // y1 z1 x2 y2
        const float4 Cv = p4[2];  // z2 x3 y3 z3
        unsigned v0, v1, v2, v3;
        if (BYTE) {
            const unsigned vw = *(const unsigned*)((const unsigned char*)vpv + n0);
            v0 = vw & 0xffu; v1 = vw & 0xff00u; v2 = vw & 0xff0000u; v3 = vw & 0xff000000u;
        } else {
            const uint4 vw = *(const uint4*)((const unsigned*)vpv + n0);
            v0 = vw.x; v1 = vw.y; v2 = vw.z; v3 = vw.w;
        }
        float dx, dy, dz, d2;
        dx = A.x - kx; dy = A.y - ky; dz = A.z - kz;
        d2 = fmaf(dz, dz, fmaf(dy, dy, dx * dx));
        const unsigned kv0 = v0 ? ((__float_as_uint(d2) & 0xFFFFE000u) | (unsigned)(n0 + 0)) : 0xFFFFFFFFu;
        dx = A.w - kx; dy = Bv.x - ky; dz = Bv.y - kz;
        d2 = fmaf(dz, dz, fmaf(dy, dy, dx * dx));
        const unsigned kv1 = v1 ? ((__float_as_uint(d2) & 0xFFFFE000u) | (unsigned)(n0 + 1)) : 0xFFFFFFFFu;
        dx = Bv.z - kx; dy = Bv.w - ky; dz = Cv.x - kz;
        d2 = fmaf(dz, dz, fmaf(dy, dy, dx * dx));
        const unsigned kv2 = v2 ? ((__float_as_uint(d2) & 0xFFFFE000u) | (unsigned)(n0 + 2)) : 0xFFFFFFFFu;
        dx = Cv.y - kx; dy = Cv.z - ky; dz = Cv.w - kz;
        d2 = fmaf(dz, dz, fmaf(dy, dy, dx * dx));
        const unsigned kv3 = v3 ? ((__float_as_uint(d2) & 0xFFFFE000u) | (unsigned)(n0 + 3)) : 0xFFFFFFFFu;
        insert8(sa, kv0);
        insert8(sa, kv1);
        insert8(sa, kv2);
        insert8(sa, kv3);
    }
}

// Per-wave LDS slice, phase-overlaid. 5 KB/wave, 20 KB/block -> 8 blocks/CU.
struct Slice {
    union {                       // 2 KB
        unsigned cand[8 * 64];    //   phase 1 merge
        float    w[NBR_ * CMID];  //   phase 2a-2b
        float    hf_pad[512];
    } A;
    union {                       // 2 KB
        float nf[NBR_ * CIN];     //   phase 2a-2b
        struct { float hp[4 * FHID]; float hf[FHID]; } h; // phase 2c-2d
    } Bv;
    union {                       // 1 KB
        unsigned slot[NBR_];      //   refine -> 2a
        float    e[CMID * CIN];   //   2b -> 2c
    } C;
};

__global__ __launch_bounds__(256, 6) void pc_main_kernel(
    const float* __restrict__ keys,   // [B,K,3]
    const float* __restrict__ points, // [B,N,3]
    const float* __restrict__ feats,  // [B,N,CIN]
    const void*  __restrict__ validp, // [B,K,N] u8 or u32
    const float* __restrict__ ww1, const float* __restrict__ wb1,
    const float* __restrict__ ww2, const float* __restrict__ wb2,
    const float* __restrict__ fw1, const float* __restrict__ fb1,
    const float* __restrict__ fw2, const float* __restrict__ fb2,
    float* __restrict__ out,          // [B,K,COUT]
    const int* __restrict__ flagp)
{
    __shared__ Slice sl[4];

    const int lane = threadIdx.x & 63;
    const int wv   = threadIdx.x >> 6;
    const int row  = (blockIdx.x << 2) | wv;   // b*K + k
    const int b    = row >> 11;                // K = 2048
    Slice& S = sl[wv];

    const float kx = keys[row * 3 + 0];
    const float ky = keys[row * 3 + 1];
    const float kz = keys[row * 3 + 2];
    const float* pts = points + (size_t)b * N_ * 3;
    const int flag = *flagp;

    // ---------------- phase 1: per-lane top-8 over 128 points (4/iter) ----------------
    unsigned sa[8];
#pragma unroll
    for (int i = 0; i < 8; ++i) sa[i] = 0xFFFFFFFFu;

    const size_t vbase = (size_t)row * N_;
    if (flag) {
        scan_pts4<1>(pts, (const void*)((const unsigned char*)validp + vbase), kx, ky, kz, lane, sa);
    } else {
        scan_pts4<0>(pts, (const void*)((const unsigned*)validp + vbase), kx, ky, kz, lane, sa);
    }

    // -------- merge: NCAND-round wave-wide extract-min (candidate superset) --------
#pragma unroll
    for (int i = 0; i < 8; ++i) S.A.cand[i * 64 + lane] = sa[i];
    __syncthreads();

    unsigned cur   = sa[0];
    int      head  = 0;
    unsigned mykey = 0xFFFFFFFFu;
#pragma unroll 4
    for (int r = 0; r < NCAND; ++r) {
        unsigned t = cur;
#pragma unroll
        for (int off = 1; off < 64; off <<= 1)
            t = umin_(t, (unsigned)__shfl_xor((int)t, off, 64));
        if (lane == r) mykey = t;   // lane r owns the r-th smallest (truncated order)
        if (cur == t) {             // unique winner (idx embedded in key)
            ++head;
            cur = (head < 8) ? S.A.cand[head * 64 + lane] : 0xFFFFFFFFu;
        }
    }

    // -------- refine: exact rank of the NCAND candidates by full-precision d^2 --------
    if (lane < NBR_) S.C.slot[lane] = 0xFFFFFFFFu;
    __syncthreads();   // also orders merge-reads of cand before 2a's w-overlay writes

    {
        const bool fin  = (mykey < 0xF0000000u);
        const int  cidx = (int)(mykey & 8191u);
        float cd2 = 3.0e38f;
        if (fin) {
            const float cdx = pts[cidx * 3 + 0] - kx;
            const float cdy = pts[cidx * 3 + 1] - ky;
            const float cdz = pts[cidx * 3 + 2] - kz;
            cd2 = fmaf(cdz, cdz, fmaf(cdy, cdy, cdx * cdx));
        }
        const unsigned long long fkey =
            fin ? (((unsigned long long)__float_as_uint(cd2) << 13) | (unsigned long long)cidx)
                : ~0ull;
        int rank = 0;
#pragma unroll 8
        for (int j = 0; j < NCAND; ++j) {
            const unsigned long long fj = (unsigned long long)__shfl((long long)fkey, j, 64);
            rank += (fj < fkey) ? 1 : 0;
        }
        if (fin && rank < NBR_)
            S.C.slot[rank] = mykey;   // ranks of finite candidates are unique
    }
    __syncthreads();

    // ---------------- phase 2a: per-neighbor weight MLP ----------------
    // lane -> (neighbor q = lane&31, half = lane>>5 owning 8 of 16 outputs)
    const int q    = lane & 31;
    const int half = lane >> 5;
    const unsigned skey = S.C.slot[q];
    const int   nidx = (int)(skey & 8191u);
    const float vf   = (skey < 0xF0000000u) ? 1.0f : 0.0f;

    const float rx = pts[nidx * 3 + 0] - kx;
    const float ry = pts[nidx * 3 + 1] - ky;
    const float rz = pts[nidx * 3 + 2] - kz;

    float wacc[8];
    {
        const float4 b0 = *(const float4*)&wb2[half * 8 + 0];
        const float4 b1 = *(const float4*)&wb2[half * 8 + 4];
        wacc[0] = b0.x; wacc[1] = b0.y; wacc[2] = b0.z; wacc[3] = b0.w;
        wacc[4] = b1.x; wacc[5] = b1.y; wacc[6] = b1.z; wacc[7] = b1.w;
    }

#pragma unroll 8
    for (int j = 0; j < WHID; ++j) {
        float hj = fmaf(rx, ww1[j], fmaf(ry, ww1[WHID + j], fmaf(rz, ww1[2 * WHID + j], wb1[j])));
        hj = fmaxf(hj, 0.0f);
        const float4 wa = *(const float4*)&ww2[j * CMID + half * 8 + 0];
        const float4 wb = *(const float4*)&ww2[j * CMID + half * 8 + 4];
        wacc[0] = fmaf(hj, wa.x, wacc[0]);
        wacc[1] = fmaf(hj, wa.y, wacc[1]);
        wacc[2] = fmaf(hj, wa.z, wacc[2]);
        wacc[3] = fmaf(hj, wa.w, wacc[3]);
        wacc[4] = fmaf(hj, wb.x, wacc[4]);
        wacc[5] = fmaf(hj, wb.y, wacc[5]);
        wacc[6] = fmaf(hj, wb.z, wacc[6]);
        wacc[7] = fmaf(hj, wb.w, wacc[7]);
    }
#pragma unroll
    for (int m = 0; m < 8; ++m) wacc[m] *= vf;

    *(float4*)&S.A.w[q * CMID + half * 8 + 0] = make_float4(wacc[0], wacc[1], wacc[2], wacc[3]);
    *(float4*)&S.A.w[q * CMID + half * 8 + 4] = make_float4(wacc[4], wacc[5], wacc[6], wacc[7]);

    // neighbor feats (8 channels per lane-half); masking w alone is sufficient
    const float* fp = feats + ((size_t)b * N_ + (size_t)nidx) * CIN + half * 8;
    *(float4*)&S.Bv.nf[q * CIN + half * 8 + 0] = *(const float4*)(fp + 0);
    *(float4*)&S.Bv.nf[q * CIN + half * 8 + 4] = *(const float4*)(fp + 4);
    __syncthreads();

    // ---------------- phase 2b: e[m][c] = sum_q w[q][m]*nf[q][c] ----------------
    {
        const int m  = lane >> 2;  // 0..15
        const int c4 = lane & 3;   // c block
        float4 eacc = make_float4(0.f, 0.f, 0.f, 0.f);
#pragma unroll
        for (int qq = 0; qq < NBR_; ++qq) {
            const float  wq = S.A.w[qq * CMID + m];
            const float4 f  = *(const float4*)&S.Bv.nf[qq * CIN + c4 * 4];
            eacc.x = fmaf(wq, f.x, eacc.x);
            eacc.y = fmaf(wq, f.y, eacc.y);
            eacc.z = fmaf(wq, f.z, eacc.z);
            eacc.w = fmaf(wq, f.w, eacc.w);
        }
        *(float4*)&S.C.e[m * CIN + c4 * 4] = eacc;
    }
    __syncthreads();

    // ---------------- phase 2c: hf = relu(e_flat @ fw1 + fb1) ----------------
    {
        const int g  = lane >> 4;  // e-chunk 64*g..64*g+63
        const int t4 = lane & 15;  // outputs 4*t4..4*t4+3
        float a0 = 0.f, a1 = 0.f, a2 = 0.f, a3 = 0.f;
#pragma unroll 8
        for (int i = 0; i < 64; ++i) {
            const float  ev = S.C.e[g * 64 + i];
            const float4 wv2 = *(const float4*)&fw1[(size_t)(g * 64 + i) * FHID + t4 * 4];
            a0 = fmaf(ev, wv2.x, a0);
            a1 = fmaf(ev, wv2.y, a1);
            a2 = fmaf(ev, wv2.z, a2);
            a3 = fmaf(ev, wv2.w, a3);
        }
        *(float4*)&S.Bv.h.hp[g * FHID + t4 * 4] = make_float4(a0, a1, a2, a3);
    }
    __syncthreads();

    {
        float hf = fb1[lane] + S.Bv.h.hp[lane] + S.Bv.h.hp[FHID + lane]
                 + S.Bv.h.hp[2 * FHID + lane] + S.Bv.h.hp[3 * FHID + lane];
        S.Bv.h.hf[lane] = fmaxf(hf, 0.0f);
    }
    __syncthreads();

    // ---------------- phase 2d: out = hf @ fw2 + fb2 ----------------
    {
        float oacc = fb2[lane];
#pragma unroll 8
        for (int j = 0; j < FHID; ++j)
            oacc = fmaf(S.Bv.h.hf[j], fw2[(size_t)j * COUT + lane], oacc);
        out[(size_t)row * COUT + lane] = oacc;
    }
}

extern "C" void kernel_launch(void* const* d_in, const int* in_sizes, int n_in,
                              void* d_out, int out_size, void* d_ws, size_t ws_size,
                              hipStream_t stream) {
    const float* keys   = (const float*)d_in[0];
    const float* points = (const float*)d_in[1];
    const float* feats  = (const float*)d_in[2];
    const void*  valid  = d_in[3];
    const float* ww1 = (const float*)d_in[4];
    const float* wb1 = (const float*)d_in[5];
    const float* ww2 = (const float*)d_in[6];
    const float* wb2 = (const float*)d_in[7];
    const float* fw1 = (const float*)d_in[8];
    const float* fb1 = (const float*)d_in[9];
    const float* fw2 = (const float*)d_in[10];
    const float* fb2 = (const float*)d_in[11];
    float* out = (float*)d_out;
    int*   flag = (int*)d_ws;

    pc_detect_kernel<<<1, 64, 0, stream>>>((const unsigned*)valid, flag);
    pc_main_kernel<<<(B_ * K_) / 4, 256, 0, stream>>>(keys, points, feats, valid,
                                                      ww1, wb1, ww2, wb2,
                                                      fw1, fb1, fw2, fb2,
                                                      out, flag);
}